// Round 21
// baseline (153.004 us; speedup 1.0000x reference)
//
#include <hip/hip_runtime.h>
#include <hip/hip_cooperative_groups.h>
namespace cg = cooperative_groups;

// Encoder block: B=128, S=512, D=24, H=4, HD=6, DFF=48, fp32 in/out.
// R21: cooperative fusion retry. R20's failure diagnosed as occupancy:
// 512-thr blocks needed 2 blocks/CU => VGPR<=128 (4 waves/SIMD) -> coop
// validation failed, nothing launched. Fix: 256-thr blocks (grid 512) =>
// 2 blocks/CU needs only 2 waves/SIMD => VGPR<=256 (trivially fits).
// Phase A: attn, 4 waves x 4 tiles (same math). Phase B: R12-proven
// 256-thread ffn. PLUS capture-safe fallback: if coop launch returns an
// error (enqueues nothing), launch the proven R19 two-kernel path.

#define DD   24
#define HH   4
#define HDD  6
#define DFFN 48
#define SS   512
#define BB   128
#define NTOK (BB*SS)   // 65536
#define NBH  (BB*HH)   // 512

typedef unsigned short ushort_t;
typedef unsigned int   uint_t;
typedef __bf16  bf16x8  __attribute__((ext_vector_type(8)));
typedef float   f32x16  __attribute__((ext_vector_type(16)));

static constexpr float EPSV   = 1e-5f;
static constexpr float QSCALE = (float)(1.4426950408889634 / 2.449489742783178);

#define VT_PER_BH (16*2*9*2*8)   // 4608
#define VT_PER_KT (2*9*2*8)      // 576
#define VT_PER_M  (9*2*8)        // 144

#define XPAD 28
#define HPAD 52

__device__ __forceinline__ uint_t cvtpk(float lo, float hi) {
    uint_t r;
    asm("v_cvt_pk_bf16_f32 %0, %1, %2" : "=v"(r) : "v"(lo), "v"(hi));
    return r;
}
__device__ __forceinline__ ushort_t f2bf(float f) {
    return (ushort_t)cvtpk(f, 0.0f);
}
__device__ __forceinline__ uint_t pexp2(float a, float b) {
    uint_t ua = __builtin_bit_cast(uint_t, fmaf(a, 128.0f, 8404859.0f));
    uint_t ub = __builtin_bit_cast(uint_t, fmaf(b, 128.0f, 8404859.0f));
    return __builtin_amdgcn_perm(ub, ua, 0x05040100u);
}
__device__ __forceinline__ void qload3(const float* row, int hi,
                                       float4& f0, float4& f1, float4& f2) {
    f0 = *(const float4*)(row + 4*hi);
    f1 = *(const float4*)(row + 8 + 4*hi);
    f2 = *(const float4*)(row + 16 + 4*hi);
}
__device__ __forceinline__ uint4 frag_kt0(float4 f0, float4 f1) {
    return make_uint4(cvtpk(f0.x,f0.y), cvtpk(f0.z,f0.w),
                      cvtpk(f1.x,f1.y), cvtpk(f1.z,f1.w));
}
__device__ __forceinline__ uint4 frag_kt1(float4 f2) {
    return make_uint4(cvtpk(f2.x,f2.y), cvtpk(f2.z,f2.w), 0u, 0u);
}
__device__ __forceinline__ bf16x8 asbf(uint4 u) { return __builtin_bit_cast(bf16x8, u); }

// union smem: attn Qs[0,8K) Ks[8K,16K) Vs[16K,25600) sWat[25600,27328)
//             ffn  xL[0,14336) hL[14336,40960) FL1[40960,53248)
#define SMEM_BYTES 53248

// ==================== fused cooperative kernel (256 thr) ====================
__global__ __launch_bounds__(256, 2) void fused_kernel(
    const float* __restrict__ x,  const float* __restrict__ Wq,
    const float* __restrict__ Wk, const float* __restrict__ Wv,
    const float* __restrict__ Wo, const float* __restrict__ W1,
    const float* __restrict__ W2,
    const float* __restrict__ g1, const float* __restrict__ b1,
    const float* __restrict__ g2, const float* __restrict__ b2,
    float* __restrict__ Oa, float* __restrict__ out)
{
    __shared__ alignas(16) unsigned char smem[SMEM_BYTES];
    __shared__ float sW2t[DFFN*DD];
    __shared__ float sg1[DD], sb1[DD], sg2[DD], sb2[DD];

    int tid  = threadIdx.x;
    int lane = tid & 63;
    int wv   = tid >> 6;                 // 0..3
    int bh = blockIdx.x;
    int b = bh >> 2, h = bh & 3;
    int hi = lane >> 5;
    int c  = lane & 31;

    ushort_t* Qs   = (ushort_t*)smem;
    ushort_t* Ks   = (ushort_t*)(smem + 8192);
    ushort_t* Vs   = (ushort_t*)(smem + 16384);
    float*    sWat = (float*)(smem + 25600);

    for (int i = tid; i < DFFN*DD; i += 256) {
        int jj = i / DD, o = i - jj*DD;
        sW2t[i] = W2[o*DFFN + jj];
    }
    if (tid < DD) {
        sg1[tid] = g1[tid]; sb1[tid] = b1[tid];
        sg2[tid] = g2[tid]; sb2[tid] = b2[tid];
    }
    for (int i = tid; i < 3*HDD*DD; i += 256) {
        int m = i / (HDD*DD), r = (i % (HDD*DD)) / DD, cc = i % DD;
        const float* Wm = (m == 0) ? Wq : (m == 1) ? Wk : Wv;
        sWat[i] = Wm[(h*HDD + r)*DD + cc];
    }
    __syncthreads();

    // ---- phase A0: qkv into LDS (each thread: tokens tid, tid+256) ----
    for (int s = tid; s < SS; s += 256) {
        float xv[DD];
        const float4* xp = (const float4*)(x + ((size_t)b*SS + s)*DD);
#pragma unroll
        for (int i = 0; i < DD/4; ++i) {
            float4 v = xp[i];
            xv[4*i+0] = v.x; xv[4*i+1] = v.y; xv[4*i+2] = v.z; xv[4*i+3] = v.w;
        }
        float q[HDD], k[HDD], v[HDD];
#pragma unroll
        for (int d = 0; d < HDD; ++d) {
            float aq = 0.f, ak = 0.f, av = 0.f;
#pragma unroll
            for (int i = 0; i < DD; ++i) {
                aq = fmaf(xv[i], sWat[0*HDD*DD + d*DD + i], aq);
                ak = fmaf(xv[i], sWat[1*HDD*DD + d*DD + i], ak);
                av = fmaf(xv[i], sWat[2*HDD*DD + d*DD + i], av);
            }
            q[d] = aq * QSCALE; k[d] = ak; v[d] = av;
        }
        uint4 qs_, ks_;
        qs_.x = cvtpk(q[0], q[1]); qs_.y = cvtpk(q[2], q[3]); qs_.z = cvtpk(q[4], q[5]); qs_.w = 0;
        ks_.x = cvtpk(k[0], k[1]); ks_.y = cvtpk(k[2], k[3]); ks_.z = cvtpk(k[4], k[5]); ks_.w = 0;
        *(uint4*)(Qs + s*8) = qs_;
        *(uint4*)(Ks + s*8) = ks_;
        int kt  = s >> 5;
        int kl  = s & 31;
        int m   = (kl >> 4) & 1;
        int k16 = kl & 15;
        int hi2 = (k16 >> 2) & 1;
        int j2  = (k16 & 3) + ((k16 >> 3) << 2);
        ushort_t* vp = Vs + kt*VT_PER_KT + m*VT_PER_M + hi2*8 + j2;
#pragma unroll
        for (int d = 0; d < HDD; ++d) vp[d*16] = f2bf(v[d]);
        vp[6*16] = 0x3F80u;
        vp[7*16] = 0;
        vp[8*16] = 0x3F80u;
    }
    __syncthreads();

    // ---- phase A1: MFMA attention tiles (4 waves x 4 tiles) ----
    {
        const ushort_t* Vp = Vs + (c*2 + hi)*8;
        bool vld = (c < 9);
        f32x16 Z;
#pragma unroll
        for (int i = 0; i < 16; ++i) Z[i] = 0.f;

#pragma unroll
        for (int ti = 0; ti < 4; ++ti) {
            int tile = wv*4 + ti;   // 0..15
            int q0 = tile * 32;
            uint4 qf = {0,0,0,0};
            if (hi == 0) qf = *(const uint4*)(Qs + (q0 + c)*8);
            bf16x8 bq = __builtin_bit_cast(bf16x8, qf);

            f32x16 O;
#pragma unroll
            for (int i = 0; i < 16; ++i) O[i] = 0.f;

#pragma unroll 2
            for (int kt = 0; kt < 16; ++kt) {
                uint4 kf = {0,0,0,0};
                if (hi == 0) kf = *(const uint4*)(Ks + (kt*32 + c)*8);
                f32x16 S = __builtin_amdgcn_mfma_f32_32x32x16_bf16(
                    __builtin_bit_cast(bf16x8, kf), bq, Z, 0, 0, 0);
                uint4 fa, fb;
                fa.x = pexp2(S[0],  S[1]);
                fa.y = pexp2(S[2],  S[3]);
                fa.z = pexp2(S[4],  S[5]);
                fa.w = pexp2(S[6],  S[7]);
                fb.x = pexp2(S[8],  S[9]);
                fb.y = pexp2(S[10], S[11]);
                fb.z = pexp2(S[12], S[13]);
                fb.w = pexp2(S[14], S[15]);
                uint4 va = {0,0,0,0}, vb = {0,0,0,0};
                if (vld) {
                    const ushort_t* vp = Vp + kt*VT_PER_KT;
                    va = *(const uint4*)(vp);
                    vb = *(const uint4*)(vp + VT_PER_M);
                }
                O = __builtin_amdgcn_mfma_f32_32x32x16_bf16(
                    __builtin_bit_cast(bf16x8, va), __builtin_bit_cast(bf16x8, fa), O, 0, 0, 0);
                O = __builtin_amdgcn_mfma_f32_32x32x16_bf16(
                    __builtin_bit_cast(bf16x8, vb), __builtin_bit_cast(bf16x8, fb), O, 0, 0, 0);
            }
            float inv = 1.0f / (hi ? O[2] : O[4]);
            float* op = Oa + ((size_t)b*SS + q0 + c)*DD + h*HDD;
            if (hi == 0) {
                *(float2*)(op + 0) = make_float2(O[0]*inv, O[1]*inv);
                *(float2*)(op + 2) = make_float2(O[2]*inv, O[3]*inv);
            } else {
                *(float2*)(op + 4) = make_float2(O[0]*inv, O[1]*inv);
            }
        }
    }

    // ---- preload ffn A-frags (latency hides under grid sync) ----
    uint4 aWo0 = {0,0,0,0}, aWo1 = {0,0,0,0};
    uint4 aW1r0k0, aW1r0k1;
    uint4 aW1r1k0 = {0,0,0,0}, aW1r1k1 = {0,0,0,0};
    if (c < DD) {
        float4 w0,w1,w2;
        qload3(Wo + (size_t)c*DD, hi, w0,w1,w2);
        aWo0 = frag_kt0(w0,w1); aWo1 = frag_kt1(w2);
    }
    {
        float4 w0,w1,w2;
        qload3(W1 + (size_t)c*DD, hi, w0,w1,w2);
        aW1r0k0 = frag_kt0(w0,w1); aW1r0k1 = frag_kt1(w2);
    }
    if (c < 16) {
        float4 w0,w1,w2;
        qload3(W1 + (size_t)(32 + c)*DD, hi, w0,w1,w2);
        aW1r1k0 = frag_kt0(w0,w1); aW1r1k1 = frag_kt1(w2);
    }

    // ================= grid-wide sync: all Oa visible ====================
    __threadfence();
    cg::this_grid().sync();

    // ========== phase B: ffn on tokens [bh*128, bh*128+128) (R12) ==========
    float (*xL)[XPAD] = (float (*)[XPAD])smem;
    float (*hL)[HPAD] = (float (*)[HPAD])(smem + 14336);
    float (*FL1)[DD]  = (float (*)[DD])(smem + 40960);

    f32x16 Z;
#pragma unroll
    for (int i = 0; i < 16; ++i) Z[i] = 0.f;

    int tok = wv*32 + c;                    // 0..127
    size_t tc = (size_t)bh*128 + tok;

    float4 oa0, oa1, oa2, xr0, xr1, xr2;
    qload3(Oa + tc*DD, hi, oa0, oa1, oa2);
    qload3(x  + tc*DD, hi, xr0, xr1, xr2);
    f32x16 C = __builtin_amdgcn_mfma_f32_32x32x16_bf16(asbf(aWo0), asbf(frag_kt0(oa0,oa1)), Z, 0,0,0);
    C = __builtin_amdgcn_mfma_f32_32x32x16_bf16(asbf(aWo1), asbf(frag_kt1(oa2)), C, 0,0,0);
    *(float4*)&xL[tok][4*hi]      = make_float4(C[0]+xr0.x, C[1]+xr0.y, C[2]+xr0.z, C[3]+xr0.w);
    *(float4*)&xL[tok][8 + 4*hi]  = make_float4(C[4]+xr1.x, C[5]+xr1.y, C[6]+xr1.z, C[7]+xr1.w);
    *(float4*)&xL[tok][16 + 4*hi] = make_float4(C[8]+xr2.x, C[9]+xr2.y, C[10]+xr2.z, C[11]+xr2.w);
    __syncthreads();

    if (tid < 128) {
        float v[DD], mu = 0.f;
#pragma unroll
        for (int i = 0; i < DD; ++i) { v[i] = xL[tid][i]; mu += v[i]; }
        mu *= (1.0f/DD);
        float vv = 0.f;
#pragma unroll
        for (int i = 0; i < DD; ++i) { float d = v[i]-mu; vv = fmaf(d,d,vv); }
        float rs = rsqrtf(vv*(1.0f/DD) + EPSV);
#pragma unroll
        for (int i = 0; i < DD; ++i) xL[tid][i] = (v[i]-mu)*rs*sg1[i] + sb1[i];
    }
    __syncthreads();

    float4 xa = *(const float4*)&xL[tok][4*hi];
    float4 xb = *(const float4*)&xL[tok][8 + 4*hi];
    float4 xc = *(const float4*)&xL[tok][16 + 4*hi];
    uint4 bx0 = frag_kt0(xa, xb), bx1 = frag_kt1(xc);
    f32x16 H0 = __builtin_amdgcn_mfma_f32_32x32x16_bf16(asbf(aW1r0k0), asbf(bx0), Z, 0,0,0);
    H0 = __builtin_amdgcn_mfma_f32_32x32x16_bf16(asbf(aW1r0k1), asbf(bx1), H0, 0,0,0);
    f32x16 H1 = __builtin_amdgcn_mfma_f32_32x32x16_bf16(asbf(aW1r1k0), asbf(bx0), Z, 0,0,0);
    H1 = __builtin_amdgcn_mfma_f32_32x32x16_bf16(asbf(aW1r1k1), asbf(bx1), H1, 0,0,0);
    *(float4*)&hL[tok][4*hi]      = make_float4(fmaxf(H0[0],0.f),  fmaxf(H0[1],0.f),  fmaxf(H0[2],0.f),  fmaxf(H0[3],0.f));
    *(float4*)&hL[tok][8 + 4*hi]  = make_float4(fmaxf(H0[4],0.f),  fmaxf(H0[5],0.f),  fmaxf(H0[6],0.f),  fmaxf(H0[7],0.f));
    *(float4*)&hL[tok][16 + 4*hi] = make_float4(fmaxf(H0[8],0.f),  fmaxf(H0[9],0.f),  fmaxf(H0[10],0.f), fmaxf(H0[11],0.f));
    *(float4*)&hL[tok][24 + 4*hi] = make_float4(fmaxf(H0[12],0.f), fmaxf(H0[13],0.f), fmaxf(H0[14],0.f), fmaxf(H0[15],0.f));
    *(float4*)&hL[tok][32 + 4*hi] = make_float4(fmaxf(H1[0],0.f),  fmaxf(H1[1],0.f),  fmaxf(H1[2],0.f),  fmaxf(H1[3],0.f));
    *(float4*)&hL[tok][40 + 4*hi] = make_float4(fmaxf(H1[4],0.f),  fmaxf(H1[5],0.f),  fmaxf(H1[6],0.f),  fmaxf(H1[7],0.f));
    __syncthreads();

    float fp[DD];
    {
        int htok = tid & 127, half = tid >> 7;
        float hreg[DD];
#pragma unroll
        for (int i = 0; i < 6; ++i) {
            float4 t4 = *(const float4*)&hL[htok][half*24 + 4*i];
            hreg[4*i+0]=t4.x; hreg[4*i+1]=t4.y; hreg[4*i+2]=t4.z; hreg[4*i+3]=t4.w;
        }
#pragma unroll
        for (int o = 0; o < DD; ++o) fp[o] = 0.f;
        for (int j = 0; j < DFFN/2; ++j) {
            int jj = half*(DFFN/2) + j;
            const float* w2r = &sW2t[jj*DD];
#pragma unroll
            for (int o = 0; o < DD; ++o) fp[o] = fmaf(hreg[j], w2r[o], fp[o]);
        }
        if (half) {
#pragma unroll
            for (int o = 0; o < DD; ++o) FL1[htok][o] = fp[o];
        }
    }
    __syncthreads();

    if (tid < 128) {
        float f2[DD], mu = 0.f;
#pragma unroll
        for (int o = 0; o < DD; ++o) {
            float fo = fmaxf(fp[o] + FL1[tid][o], 0.f) + xL[tid][o];
            f2[o] = fo; mu += fo;
        }
        mu *= (1.0f/DD);
        float vv = 0.f;
#pragma unroll
        for (int o = 0; o < DD; ++o) { float d = f2[o]-mu; vv = fmaf(d,d,vv); }
        float rs = rsqrtf(vv*(1.0f/DD) + EPSV);
        float ov[DD];
#pragma unroll
        for (int o = 0; o < DD; ++o) ov[o] = (f2[o]-mu)*rs*sg2[o] + sb2[o];
        float4* op = (float4*)(out + ((size_t)bh*128 + tid)*DD);
#pragma unroll
        for (int i = 0; i < DD/4; ++i)
            op[i] = make_float4(ov[4*i+0], ov[4*i+1], ov[4*i+2], ov[4*i+3]);
    }
}

// ==================== fallback kernels (R19, proven) ====================
__global__ __launch_bounds__(512, 4) void attn_kernel(
    const float* __restrict__ x,  const float* __restrict__ Wq,
    const float* __restrict__ Wk, const float* __restrict__ Wv,
    float* __restrict__ Oa)
{
    __shared__ ushort_t Qs[SS*8];
    __shared__ ushort_t Ks[SS*8];
    __shared__ ushort_t Vs[VT_PER_BH];
    __shared__ float    sW[3*HDD*DD];

    int tid  = threadIdx.x;
    int lane = tid & 63;
    int wv   = tid >> 6;
    int bh = blockIdx.x;
    int b = bh >> 2, h = bh & 3;
    int hi = lane >> 5;
    int c  = lane & 31;

    if (tid < 3*HDD*DD) {
        int m = tid / (HDD*DD), r = (tid % (HDD*DD)) / DD, cc = tid % DD;
        const float* Wm = (m == 0) ? Wq : (m == 1) ? Wk : Wv;
        sW[tid] = Wm[(h*HDD + r)*DD + cc];
    }
    __syncthreads();
    {
        int s = tid;
        float xv[DD];
        const float4* xp = (const float4*)(x + ((size_t)b*SS + s)*DD);
#pragma unroll
        for (int i = 0; i < DD/4; ++i) {
            float4 v = xp[i];
            xv[4*i+0] = v.x; xv[4*i+1] = v.y; xv[4*i+2] = v.z; xv[4*i+3] = v.w;
        }
        float q[HDD], k[HDD], v[HDD];
#pragma unroll
        for (int d = 0; d < HDD; ++d) {
            float aq = 0.f, ak = 0.f, av = 0.f;
#pragma unroll
            for (int i = 0; i < DD; ++i) {
                aq = fmaf(xv[i], sW[0*HDD*DD + d*DD + i], aq);
                ak = fmaf(xv[i], sW[1*HDD*DD + d*DD + i], ak);
                av = fmaf(xv[i], sW[2*HDD*DD + d*DD + i], av);
            }
            q[d] = aq * QSCALE; k[d] = ak; v[d] = av;
        }
        uint4 qs_, ks_;
        qs_.x = cvtpk(q[0], q[1]); qs_.y = cvtpk(q[2], q[3]); qs_.z = cvtpk(q[4], q[5]); qs_.w = 0;
        ks_.x = cvtpk(k[0], k[1]); ks_.y = cvtpk(k[2], k[3]); ks_.z = cvtpk(k[4], k[5]); ks_.w = 0;
        *(uint4*)(Qs + s*8) = qs_;
        *(uint4*)(Ks + s*8) = ks_;
        int kt  = s >> 5;
        int kl  = s & 31;
        int m   = (kl >> 4) & 1;
        int k16 = kl & 15;
        int hi2 = (k16 >> 2) & 1;
        int j2  = (k16 & 3) + ((k16 >> 3) << 2);
        ushort_t* vp = Vs + kt*VT_PER_KT + m*VT_PER_M + hi2*8 + j2;
#pragma unroll
        for (int d = 0; d < HDD; ++d) vp[d*16] = f2bf(v[d]);
        vp[6*16] = 0x3F80u;
        vp[7*16] = 0;
        vp[8*16] = 0x3F80u;
    }
    __syncthreads();

    const ushort_t* Vp = Vs + (c*2 + hi)*8;
    bool vld = (c < 9);
    f32x16 Z;
#pragma unroll
    for (int i = 0; i < 16; ++i) Z[i] = 0.f;

#pragma unroll
    for (int ti = 0; ti < 2; ++ti) {
        int tile = wv*2 + ti;
        int q0 = tile * 32;
        uint4 qf = {0,0,0,0};
        if (hi == 0) qf = *(const uint4*)(Qs + (q0 + c)*8);
        bf16x8 bq = __builtin_bit_cast(bf16x8, qf);
        f32x16 O;
#pragma unroll
        for (int i = 0; i < 16; ++i) O[i] = 0.f;
#pragma unroll 2
        for (int kt = 0; kt < 16; ++kt) {
            uint4 kf = {0,0,0,0};
            if (hi == 0) kf = *(const uint4*)(Ks + (kt*32 + c)*8);
            f32x16 S = __builtin_amdgcn_mfma_f32_32x32x16_bf16(
                __builtin_bit_cast(bf16x8, kf), bq, Z, 0, 0, 0);
            uint4 fa, fb;
            fa.x = pexp2(S[0],  S[1]);
            fa.y = pexp2(S[2],  S[3]);
            fa.z = pexp2(S[4],  S[5]);
            fa.w = pexp2(S[6],  S[7]);
            fb.x = pexp2(S[8],  S[9]);
            fb.y = pexp2(S[10], S[11]);
            fb.z = pexp2(S[12], S[13]);
            fb.w = pexp2(S[14], S[15]);
            uint4 va = {0,0,0,0}, vb = {0,0,0,0};
            if (vld) {
                const ushort_t* vp = Vp + kt*VT_PER_KT;
                va = *(const uint4*)(vp);
                vb = *(const uint4*)(vp + VT_PER_M);
            }
            O = __builtin_amdgcn_mfma_f32_32x32x16_bf16(
                __builtin_bit_cast(bf16x8, va), __builtin_bit_cast(bf16x8, fa), O, 0, 0, 0);
            O = __builtin_amdgcn_mfma_f32_32x32x16_bf16(
                __builtin_bit_cast(bf16x8, vb), __builtin_bit_cast(bf16x8, fb), O, 0, 0, 0);
        }
        float inv = 1.0f / (hi ? O[2] : O[4]);
        float* op = Oa + ((size_t)b*SS + q0 + c)*DD + h*HDD;
        if (hi == 0) {
            *(float2*)(op + 0) = make_float2(O[0]*inv, O[1]*inv);
            *(float2*)(op + 2) = make_float2(O[2]*inv, O[3]*inv);
        } else {
            *(float2*)(op + 4) = make_float2(O[0]*inv, O[1]*inv);
        }
    }
}

#define FTOK 64
__global__ __launch_bounds__(128, 2) void ffn_kernel(
    const float* __restrict__ x,  const float* __restrict__ Oa,
    const float* __restrict__ Wo, const float* __restrict__ W1,
    const float* __restrict__ W2,
    const float* __restrict__ g1, const float* __restrict__ b1,
    const float* __restrict__ g2, const float* __restrict__ b2,
    float* __restrict__ out)
{
    __shared__ float sW2t[DFFN*DD];
    __shared__ float sg1[DD], sb1[DD], sg2[DD], sb2[DD];
    __shared__ float xLDS[FTOK][XPAD];
    __shared__ float hLDS[FTOK][HPAD];
    __shared__ float FLDS[2][FTOK][DD];

    int tid = threadIdx.x;
    for (int i = tid; i < DFFN*DD; i += 128) {
        int jj = i / DD, o = i - jj*DD;
        sW2t[i] = W2[o*DFFN + jj];
    }
    if (tid < DD) {
        sg1[tid] = g1[tid]; sb1[tid] = b1[tid];
        sg2[tid] = g2[tid]; sb2[tid] = b2[tid];
    }
    int lane = tid & 63, wv = tid >> 6;
    int hi = lane >> 5, c = lane & 31;
    int tok = wv*32 + c;
    int tc  = blockIdx.x*FTOK + tok;

    f32x16 Z;
#pragma unroll
    for (int i = 0; i < 16; ++i) Z[i] = 0.f;

    uint4 aWo0 = {0,0,0,0}, aWo1 = {0,0,0,0};
    if (c < DD) {
        float4 w0,w1,w2;
        qload3(Wo + (size_t)c*DD, hi, w0,w1,w2);
        aWo0 = frag_kt0(w0,w1); aWo1 = frag_kt1(w2);
    }
    uint4 aW1r0k0, aW1r0k1;
    {
        float4 w0,w1,w2;
        qload3(W1 + (size_t)c*DD, hi, w0,w1,w2);
        aW1r0k0 = frag_kt0(w0,w1); aW1r0k1 = frag_kt1(w2);
    }
    uint4 aW1r1k0 = {0,0,0,0}, aW1r1k1 = {0,0,0,0};
    if (c < 16) {
        float4 w0,w1,w2;
        qload3(W1 + (size_t)(32 + c)*DD, hi, w0,w1,w2);
        aW1r1k0 = frag_kt0(w0,w1); aW1r1k1 = frag_kt1(w2);
    }

    float4 oa0, oa1, oa2, xr0, xr1, xr2;
    qload3(Oa + (size_t)tc*DD, hi, oa0, oa1, oa2);
    qload3(x  + (size_t)tc*DD, hi, xr0, xr1, xr2);
    f32x16 C = __builtin_amdgcn_mfma_f32_32x32x16_bf16(asbf(aWo0), asbf(frag_kt0(oa0,oa1)), Z, 0,0,0);
    C = __builtin_amdgcn_mfma_f32_32x32x16_bf16(asbf(aWo1), asbf(frag_kt1(oa2)), C, 0,0,0);
    *(float4*)&xLDS[tok][4*hi]      = make_float4(C[0]+xr0.x, C[1]+xr0.y, C[2]+xr0.z, C[3]+xr0.w);
    *(float4*)&xLDS[tok][8 + 4*hi]  = make_float4(C[4]+xr1.x, C[5]+xr1.y, C[6]+xr1.z, C[7]+xr1.w);
    *(float4*)&xLDS[tok][16 + 4*hi] = make_float4(C[8]+xr2.x, C[9]+xr2.y, C[10]+xr2.z, C[11]+xr2.w);
    __syncthreads();

    if (tid < FTOK) {
        float v[DD], mu = 0.f;
#pragma unroll
        for (int i = 0; i < DD; ++i) { v[i] = xLDS[tid][i]; mu += v[i]; }
        mu *= (1.0f/DD);
        float vv = 0.f;
#pragma unroll
        for (int i = 0; i < DD; ++i) { float d = v[i]-mu; vv = fmaf(d,d,vv); }
        float rs = rsqrtf(vv*(1.0f/DD) + EPSV);
#pragma unroll
        for (int i = 0; i < DD; ++i) xLDS[tid][i] = (v[i]-mu)*rs*sg1[i] + sb1[i];
    }
    __syncthreads();

    float4 xa = *(const float4*)&xLDS[tok][4*hi];
    float4 xb = *(const float4*)&xLDS[tok][8 + 4*hi];
    float4 xc = *(const float4*)&xLDS[tok][16 + 4*hi];
    uint4 bx0 = frag_kt0(xa, xb), bx1 = frag_kt1(xc);
    f32x16 H0 = __builtin_amdgcn_mfma_f32_32x32x16_bf16(asbf(aW1r0k0), asbf(bx0), Z, 0,0,0);
    H0 = __builtin_amdgcn_mfma_f32_32x32x16_bf16(asbf(aW1r0k1), asbf(bx1), H0, 0,0,0);
    f32x16 H1 = __builtin_amdgcn_mfma_f32_32x32x16_bf16(asbf(aW1r1k0), asbf(bx0), Z, 0,0,0);
    H1 = __builtin_amdgcn_mfma_f32_32x32x16_bf16(asbf(aW1r1k1), asbf(bx1), H1, 0,0,0);
    *(float4*)&hLDS[tok][4*hi]      = make_float4(fmaxf(H0[0],0.f),  fmaxf(H0[1],0.f),  fmaxf(H0[2],0.f),  fmaxf(H0[3],0.f));
    *(float4*)&hLDS[tok][8 + 4*hi]  = make_float4(fmaxf(H0[4],0.f),  fmaxf(H0[5],0.f),  fmaxf(H0[6],0.f),  fmaxf(H0[7],0.f));
    *(float4*)&hLDS[tok][16 + 4*hi] = make_float4(fmaxf(H0[8],0.f),  fmaxf(H0[9],0.f),  fmaxf(H0[10],0.f), fmaxf(H0[11],0.f));
    *(float4*)&hLDS[tok][24 + 4*hi] = make_float4(fmaxf(H0[12],0.f), fmaxf(H0[13],0.f), fmaxf(H0[14],0.f), fmaxf(H0[15],0.f));
    *(float4*)&hLDS[tok][32 + 4*hi] = make_float4(fmaxf(H1[0],0.f),  fmaxf(H1[1],0.f),  fmaxf(H1[2],0.f),  fmaxf(H1[3],0.f));
    *(float4*)&hLDS[tok][40 + 4*hi] = make_float4(fmaxf(H1[4],0.f),  fmaxf(H1[5],0.f),  fmaxf(H1[6],0.f),  fmaxf(H1[7],0.f));
    __syncthreads();

    {
        int htok = tid & (FTOK-1), half = tid >> 6;
        float hreg[DD];
#pragma unroll
        for (int i = 0; i < 6; ++i) {
            float4 t4 = *(const float4*)&hLDS[htok][half*24 + 4*i];
            hreg[4*i+0]=t4.x; hreg[4*i+1]=t4.y; hreg[4*i+2]=t4.z; hreg[4*i+3]=t4.w;
        }
        float fp[DD];
#pragma unroll
        for (int o = 0; o < DD; ++o) fp[o] = 0.f;
        for (int j = 0; j < DFFN/2; ++j) {
            int jj = half*(DFFN/2) + j;
            const float* w2r = &sW2t[jj*DD];
#pragma unroll
            for (int o = 0; o < DD; ++o) fp[o] = fmaf(hreg[j], w2r[o], fp[o]);
        }
#pragma unroll
        for (int o = 0; o < DD; ++o) FLDS[half][htok][o] = fp[o];
    }
    __syncthreads();

    if (tid < FTOK) {
        float f2[DD], mu = 0.f;
#pragma unroll
        for (int o = 0; o < DD; ++o) {
            float fo = fmaxf(FLDS[0][tid][o] + FLDS[1][tid][o], 0.f) + xLDS[tid][o];
            f2[o] = fo; mu += fo;
        }
        mu *= (1.0f/DD);
        float vv = 0.f;
#pragma unroll
        for (int o = 0; o < DD; ++o) { float d = f2[o]-mu; vv = fmaf(d,d,vv); }
        float rs = rsqrtf(vv*(1.0f/DD) + EPSV);
        float ov[DD];
#pragma unroll
        for (int o = 0; o < DD; ++o) ov[o] = (f2[o]-mu)*rs*sg2[o] + sb2[o];
        float4* op = (float4*)(out + ((size_t)blockIdx.x*FTOK + tid)*DD);
#pragma unroll
        for (int i = 0; i < DD/4; ++i)
            op[i] = make_float4(ov[4*i+0], ov[4*i+1], ov[4*i+2], ov[4*i+3]);
    }
}

extern "C" void kernel_launch(void* const* d_in, const int* in_sizes, int n_in,
                              void* d_out, int out_size, void* d_ws, size_t ws_size,
                              hipStream_t stream) {
    const float* x  = (const float*)d_in[0];
    const float* Wq = (const float*)d_in[1];
    const float* Wk = (const float*)d_in[2];
    const float* Wv = (const float*)d_in[3];
    const float* Wo = (const float*)d_in[4];
    const float* W1 = (const float*)d_in[5];
    const float* W2 = (const float*)d_in[6];
    const float* g1 = (const float*)d_in[7];
    const float* b1 = (const float*)d_in[8];
    const float* g2 = (const float*)d_in[9];
    const float* b2 = (const float*)d_in[10];
    float* out = (float*)d_out;
    float* Oa  = (float*)d_ws;

    void* args[] = {(void*)&x, (void*)&Wq, (void*)&Wk, (void*)&Wv, (void*)&Wo,
                    (void*)&W1, (void*)&W2, (void*)&g1, (void*)&b1, (void*)&g2,
                    (void*)&b2, (void*)&Oa, (void*)&out};
    hipError_t err = hipLaunchCooperativeKernel((void*)fused_kernel, dim3(NBH),
                                                dim3(256), args, 0, stream);
    if (err != hipSuccess) {
        // capture-safe fallback: failed launch enqueues nothing
        attn_kernel<<<NBH, 512, 0, stream>>>(x, Wq, Wk, Wv, Oa);
        ffn_kernel<<<NTOK/FTOK, 128, 0, stream>>>(x, Oa, Wo, W1, W2,
                                                  g1, b1, g2, b2, out);
    }
}

// Round 22
// 35.147 us; speedup vs baseline: 4.3532x; 4.3532x over previous
//
#include <hip/hip_runtime.h>

// Encoder block: B=128, S=512, D=24, H=4, HD=6, DFF=48, fp32 in/out.
// R22 = R19 (proven 36.7us; R21's cooperative fusion spent ~100us in
// grid.sync -> retired) + ONE change: Oa stored as bf16. ffn converted
// Oa->bf16 anyway; converting at attn's store is bit-identical math,
// halves the Oa round-trip (12.6MB->6.3MB) and deletes 12 cvtpk/thread
// in ffn stage-1 (B-frags assemble from already-bf16 words).

#define DD   24
#define HH   4
#define HDD  6
#define DFFN 48
#define SS   512
#define BB   128
#define NTOK (BB*SS)   // 65536
#define NBH  (BB*HH)   // 512

typedef unsigned short ushort_t;
typedef unsigned int   uint_t;
typedef __bf16  bf16x8  __attribute__((ext_vector_type(8)));
typedef float   f32x16  __attribute__((ext_vector_type(16)));

static constexpr float EPSV   = 1e-5f;
static constexpr float QSCALE = (float)(1.4426950408889634 / 2.449489742783178);

// Vs geometry: [kt(16)][m(2)][d(9)][hi(2)][j(8)]  (ushort elements)
#define VT_PER_BH (16*2*9*2*8)   // 4608
#define VT_PER_KT (2*9*2*8)      // 576
#define VT_PER_M  (9*2*8)        // 144

__device__ __forceinline__ uint_t cvtpk(float lo, float hi) {
    uint_t r;
    asm("v_cvt_pk_bf16_f32 %0, %1, %2" : "=v"(r) : "v"(lo), "v"(hi));
    return r;
}
__device__ __forceinline__ ushort_t f2bf(float f) {
    return (ushort_t)cvtpk(f, 0.0f);
}
// packed-bf16 2^a,2^b via magic-add + v_perm (validated R17): 3 VALU/pair.
__device__ __forceinline__ uint_t pexp2(float a, float b) {
    uint_t ua = __builtin_bit_cast(uint_t, fmaf(a, 128.0f, 8404859.0f));
    uint_t ub = __builtin_bit_cast(uint_t, fmaf(b, 128.0f, 8404859.0f));
    return __builtin_amdgcn_perm(ub, ua, 0x05040100u);
}
__device__ __forceinline__ void qload3(const float* row, int hi,
                                       float4& f0, float4& f1, float4& f2) {
    f0 = *(const float4*)(row + 4*hi);
    f1 = *(const float4*)(row + 8 + 4*hi);
    f2 = *(const float4*)(row + 16 + 4*hi);
}
__device__ __forceinline__ uint4 frag_kt0(float4 f0, float4 f1) {
    return make_uint4(cvtpk(f0.x,f0.y), cvtpk(f0.z,f0.w),
                      cvtpk(f1.x,f1.y), cvtpk(f1.z,f1.w));
}
__device__ __forceinline__ uint4 frag_kt1(float4 f2) {
    return make_uint4(cvtpk(f2.x,f2.y), cvtpk(f2.z,f2.w), 0u, 0u);
}
__device__ __forceinline__ bf16x8 asbf(uint4 u) { return __builtin_bit_cast(bf16x8, u); }

// ------- Kernel B: fused qkv + MFMA attention; 1 block/bh; Oa -> bf16 -------
__global__ __launch_bounds__(512, 4) void attn_kernel(
    const float* __restrict__ x,  const float* __restrict__ Wq,
    const float* __restrict__ Wk, const float* __restrict__ Wv,
    ushort_t* __restrict__ Oa)
{
    __shared__ ushort_t Qs[SS*8];        // 8KB
    __shared__ ushort_t Ks[SS*8];        // 8KB
    __shared__ ushort_t Vs[VT_PER_BH];   // 9KB
    __shared__ float    sW[3*HDD*DD];    // head slices of Wq,Wk,Wv (432 f32)

    int tid  = threadIdx.x;
    int lane = tid & 63;
    int wv   = tid >> 6;                 // 0..7
    int bh = blockIdx.x;
    int b = bh >> 2, h = bh & 3;
    int hi = lane >> 5;
    int c  = lane & 31;

    if (tid < 3*HDD*DD) {
        int m = tid / (HDD*DD), r = (tid % (HDD*DD)) / DD, cc = tid % DD;
        const float* Wm = (m == 0) ? Wq : (m == 1) ? Wk : Wv;
        sW[tid] = Wm[(h*HDD + r)*DD + cc];
    }
    __syncthreads();

    // ---- phase 0: scalar qkv, one thread per token (R10-proven math) ----
    {
        int s = tid;
        float xv[DD];
        const float4* xp = (const float4*)(x + ((size_t)b*SS + s)*DD);
#pragma unroll
        for (int i = 0; i < DD/4; ++i) {
            float4 v = xp[i];
            xv[4*i+0] = v.x; xv[4*i+1] = v.y; xv[4*i+2] = v.z; xv[4*i+3] = v.w;
        }
        float q[HDD], k[HDD], v[HDD];
#pragma unroll
        for (int d = 0; d < HDD; ++d) {
            float aq = 0.f, ak = 0.f, av = 0.f;
#pragma unroll
            for (int i = 0; i < DD; ++i) {
                aq = fmaf(xv[i], sW[0*HDD*DD + d*DD + i], aq);
                ak = fmaf(xv[i], sW[1*HDD*DD + d*DD + i], ak);
                av = fmaf(xv[i], sW[2*HDD*DD + d*DD + i], av);
            }
            q[d] = aq * QSCALE; k[d] = ak; v[d] = av;
        }
        uint4 qs_, ks_;
        qs_.x = cvtpk(q[0], q[1]); qs_.y = cvtpk(q[2], q[3]); qs_.z = cvtpk(q[4], q[5]); qs_.w = 0;
        ks_.x = cvtpk(k[0], k[1]); ks_.y = cvtpk(k[2], k[3]); ks_.z = cvtpk(k[4], k[5]); ks_.w = 0;
        *(uint4*)(Qs + s*8) = qs_;
        *(uint4*)(Ks + s*8) = ks_;
        int kt  = s >> 5;
        int kl  = s & 31;
        int m   = (kl >> 4) & 1;
        int k16 = kl & 15;
        int hi2 = (k16 >> 2) & 1;
        int j2  = (k16 & 3) + ((k16 >> 3) << 2);
        ushort_t* vp = Vs + kt*VT_PER_KT + m*VT_PER_M + hi2*8 + j2;
#pragma unroll
        for (int d = 0; d < HDD; ++d) vp[d*16] = f2bf(v[d]);
        vp[6*16] = 0x3F80u;   // 1.0
        vp[7*16] = 0;
        vp[8*16] = 0x3F80u;   // 1.0
    }
    __syncthreads();

    const ushort_t* Vp = Vs + (c*2 + hi)*8;
    bool vld = (c < 9);

    f32x16 Z;
#pragma unroll
    for (int i = 0; i < 16; ++i) Z[i] = 0.f;

#pragma unroll
    for (int ti = 0; ti < 2; ++ti) {
        int tile = wv*2 + ti;   // 0..15
        int q0 = tile * 32;
        uint4 qf = {0,0,0,0};
        if (hi == 0) qf = *(const uint4*)(Qs + (q0 + c)*8);
        bf16x8 bq = __builtin_bit_cast(bf16x8, qf);

        f32x16 O;
#pragma unroll
        for (int i = 0; i < 16; ++i) O[i] = 0.f;

#pragma unroll 2
        for (int kt = 0; kt < 16; ++kt) {
            uint4 kf = {0,0,0,0};
            if (hi == 0) kf = *(const uint4*)(Ks + (kt*32 + c)*8);
            f32x16 S = __builtin_amdgcn_mfma_f32_32x32x16_bf16(
                __builtin_bit_cast(bf16x8, kf), bq, Z, 0, 0, 0);
            uint4 fa, fb;
            fa.x = pexp2(S[0],  S[1]);
            fa.y = pexp2(S[2],  S[3]);
            fa.z = pexp2(S[4],  S[5]);
            fa.w = pexp2(S[6],  S[7]);
            fb.x = pexp2(S[8],  S[9]);
            fb.y = pexp2(S[10], S[11]);
            fb.z = pexp2(S[12], S[13]);
            fb.w = pexp2(S[14], S[15]);
            uint4 va = {0,0,0,0}, vb = {0,0,0,0};
            if (vld) {
                const ushort_t* vp = Vp + kt*VT_PER_KT;
                va = *(const uint4*)(vp);
                vb = *(const uint4*)(vp + VT_PER_M);
            }
            O = __builtin_amdgcn_mfma_f32_32x32x16_bf16(
                __builtin_bit_cast(bf16x8, va), __builtin_bit_cast(bf16x8, fa), O, 0, 0, 0);
            O = __builtin_amdgcn_mfma_f32_32x32x16_bf16(
                __builtin_bit_cast(bf16x8, vb), __builtin_bit_cast(bf16x8, fb), O, 0, 0, 0);
        }
        // Oa in bf16: cvtpk(O*inv) here == ffn's old cvtpk(fp32 Oa) — bit-identical.
        float inv = 1.0f / (hi ? O[2] : O[4]);
        ushort_t* op = Oa + ((size_t)b*SS + q0 + c)*DD + h*HDD;
        if (hi == 0) {
            *(uint_t*)(op + 0) = cvtpk(O[0]*inv, O[1]*inv);
            *(uint_t*)(op + 2) = cvtpk(O[2]*inv, O[3]*inv);
        } else {
            *(uint_t*)(op + 4) = cvtpk(O[0]*inv, O[1]*inv);
        }
    }
}

// ------- Kernel C (R18): 64 tokens/block; stage1+2 MFMA, scalar LN/W2 -------
#define XPAD 28
#define HPAD 52
#define FTOK 64    // tokens per ffn block

__global__ __launch_bounds__(128, 2) void ffn_kernel(
    const float* __restrict__ x,  const ushort_t* __restrict__ Oa,
    const float* __restrict__ Wo, const float* __restrict__ W1,
    const float* __restrict__ W2,
    const float* __restrict__ g1, const float* __restrict__ b1,
    const float* __restrict__ g2, const float* __restrict__ b2,
    float* __restrict__ out)
{
    __shared__ float sW2t[DFFN*DD];      // transposed: [j=48][o=24]
    __shared__ float sg1[DD], sb1[DD], sg2[DD], sb2[DD];
    __shared__ float xLDS[FTOK][XPAD];   // stage1 out -> x1 (in-place LN1)
    __shared__ float hLDS[FTOK][HPAD];   // relu(W1 @ x1) via MFMA
    __shared__ float FLDS[2][FTOK][DD];  // W2 partial sums (per half)

    int tid = threadIdx.x;
    for (int i = tid; i < DFFN*DD; i += 128) {
        int jj = i / DD, o = i - jj*DD;
        sW2t[i] = W2[o*DFFN + jj];
    }
    if (tid < DD) {
        sg1[tid] = g1[tid]; sb1[tid] = b1[tid];
        sg2[tid] = g2[tid]; sb2[tid] = b2[tid];
    }

    int lane = tid & 63, wv = tid >> 6;     // wv in {0,1}
    int hi = lane >> 5, c = lane & 31;
    int tok = wv*32 + c;                    // block-local token 0..63
    int tc  = blockIdx.x*FTOK + tok;        // global token

    f32x16 Z;
#pragma unroll
    for (int i = 0; i < 16; ++i) Z[i] = 0.f;

    // ---- A-frags from global: Wo, W1 (proven) ----
    uint4 aWo0 = {0,0,0,0}, aWo1 = {0,0,0,0};
    if (c < DD) {
        float4 w0,w1,w2;
        qload3(Wo + (size_t)c*DD, hi, w0,w1,w2);
        aWo0 = frag_kt0(w0,w1); aWo1 = frag_kt1(w2);
    }
    uint4 aW1r0k0, aW1r0k1;                 // W1 rows 0..31 (row = c)
    {
        float4 w0,w1,w2;
        qload3(W1 + (size_t)c*DD, hi, w0,w1,w2);
        aW1r0k0 = frag_kt0(w0,w1); aW1r0k1 = frag_kt1(w2);
    }
    uint4 aW1r1k0 = {0,0,0,0}, aW1r1k1 = {0,0,0,0};   // W1 rows 32..47
    if (c < 16) {
        float4 w0,w1,w2;
        qload3(W1 + (size_t)(32 + c)*DD, hi, w0,w1,w2);
        aW1r1k0 = frag_kt0(w0,w1); aW1r1k1 = frag_kt1(w2);
    }

    // ---- stage 1: Wo @ Oa(bf16, direct) + x residual -> xLDS ----
    const ushort_t* oap = Oa + (size_t)tc*DD;
    uint2 oA = *(const uint2*)(oap + 4*hi);        // d 4hi..4hi+3
    uint2 oB = *(const uint2*)(oap + 8 + 4*hi);    // d 8+4hi..
    uint2 oC = *(const uint2*)(oap + 16 + 4*hi);   // d 16+4hi..
    uint4 bOa0 = make_uint4(oA.x, oA.y, oB.x, oB.y);
    uint4 bOa1 = make_uint4(oC.x, oC.y, 0u, 0u);
    float4 xr0, xr1, xr2;
    qload3(x + (size_t)tc*DD, hi, xr0, xr1, xr2);
    f32x16 C = __builtin_amdgcn_mfma_f32_32x32x16_bf16(asbf(aWo0), asbf(bOa0), Z, 0,0,0);
    C = __builtin_amdgcn_mfma_f32_32x32x16_bf16(asbf(aWo1), asbf(bOa1), C, 0,0,0);
    *(float4*)&xLDS[tok][4*hi]      = make_float4(C[0]+xr0.x, C[1]+xr0.y, C[2]+xr0.z, C[3]+xr0.w);
    *(float4*)&xLDS[tok][8 + 4*hi]  = make_float4(C[4]+xr1.x, C[5]+xr1.y, C[6]+xr1.z, C[7]+xr1.w);
    *(float4*)&xLDS[tok][16 + 4*hi] = make_float4(C[8]+xr2.x, C[9]+xr2.y, C[10]+xr2.z, C[11]+xr2.w);
    __syncthreads();

    // ---- scalar LN1: one thread per token, in place ----
    if (tid < FTOK) {
        float v[DD], mu = 0.f;
#pragma unroll
        for (int i = 0; i < DD; ++i) { v[i] = xLDS[tid][i]; mu += v[i]; }
        mu *= (1.0f/DD);
        float vv = 0.f;
#pragma unroll
        for (int i = 0; i < DD; ++i) { float d = v[i]-mu; vv = fmaf(d,d,vv); }
        float rs = rsqrtf(vv*(1.0f/DD) + EPSV);
#pragma unroll
        for (int i = 0; i < DD; ++i) xLDS[tid][i] = (v[i]-mu)*rs*sg1[i] + sb1[i];
    }
    __syncthreads();

    // ---- stage 2: W1 @ x1 via MFMA, relu -> hLDS ----
    float4 xa = *(const float4*)&xLDS[tok][4*hi];
    float4 xb = *(const float4*)&xLDS[tok][8 + 4*hi];
    float4 xc = *(const float4*)&xLDS[tok][16 + 4*hi];
    uint4 bx0 = frag_kt0(xa, xb), bx1 = frag_kt1(xc);
    f32x16 H0 = __builtin_amdgcn_mfma_f32_32x32x16_bf16(asbf(aW1r0k0), asbf(bx0), Z, 0,0,0);
    H0 = __builtin_amdgcn_mfma_f32_32x32x16_bf16(asbf(aW1r0k1), asbf(bx1), H0, 0,0,0);
    f32x16 H1 = __builtin_amdgcn_mfma_f32_32x32x16_bf16(asbf(aW1r1k0), asbf(bx0), Z, 0,0,0);
    H1 = __builtin_amdgcn_mfma_f32_32x32x16_bf16(asbf(aW1r1k1), asbf(bx1), H1, 0,0,0);
    *(float4*)&hLDS[tok][4*hi]      = make_float4(fmaxf(H0[0],0.f),  fmaxf(H0[1],0.f),  fmaxf(H0[2],0.f),  fmaxf(H0[3],0.f));
    *(float4*)&hLDS[tok][8 + 4*hi]  = make_float4(fmaxf(H0[4],0.f),  fmaxf(H0[5],0.f),  fmaxf(H0[6],0.f),  fmaxf(H0[7],0.f));
    *(float4*)&hLDS[tok][16 + 4*hi] = make_float4(fmaxf(H0[8],0.f),  fmaxf(H0[9],0.f),  fmaxf(H0[10],0.f), fmaxf(H0[11],0.f));
    *(float4*)&hLDS[tok][24 + 4*hi] = make_float4(fmaxf(H0[12],0.f), fmaxf(H0[13],0.f), fmaxf(H0[14],0.f), fmaxf(H0[15],0.f));
    *(float4*)&hLDS[tok][32 + 4*hi] = make_float4(fmaxf(H1[0],0.f),  fmaxf(H1[1],0.f),  fmaxf(H1[2],0.f),  fmaxf(H1[3],0.f));
    *(float4*)&hLDS[tok][40 + 4*hi] = make_float4(fmaxf(H1[4],0.f),  fmaxf(H1[5],0.f),  fmaxf(H1[6],0.f),  fmaxf(H1[7],0.f));
    __syncthreads();

    // ---- scalar W2: 2 threads/token, h hoisted to regs, sW2t broadcast ----
    {
        int htok = tid & (FTOK-1), half = tid >> 6;
        float hreg[DD];
#pragma unroll
        for (int i = 0; i < 6; ++i) {
            float4 t4 = *(const float4*)&hLDS[htok][half*24 + 4*i];
            hreg[4*i+0]=t4.x; hreg[4*i+1]=t4.y; hreg[4*i+2]=t4.z; hreg[4*i+3]=t4.w;
        }
        float fp[DD];
#pragma unroll
        for (int o = 0; o < DD; ++o) fp[o] = 0.f;
        for (int j = 0; j < DFFN/2; ++j) {
            int jj = half*(DFFN/2) + j;          // wave-uniform -> LDS broadcast
            const float* w2r = &sW2t[jj*DD];
#pragma unroll
            for (int o = 0; o < DD; ++o) fp[o] = fmaf(hreg[j], w2r[o], fp[o]);
        }
#pragma unroll
        for (int o = 0; o < DD; ++o) FLDS[half][htok][o] = fp[o];
    }
    __syncthreads();

    // ---- scalar LN2 + store: one thread per token ----
    if (tid < FTOK) {
        float f2[DD], mu = 0.f;
#pragma unroll
        for (int o = 0; o < DD; ++o) {
            float fo = fmaxf(FLDS[0][tid][o] + FLDS[1][tid][o], 0.f) + xLDS[tid][o];
            f2[o] = fo; mu += fo;
        }
        mu *= (1.0f/DD);
        float vv = 0.f;
#pragma unroll
        for (int o = 0; o < DD; ++o) { float d = f2[o]-mu; vv = fmaf(d,d,vv); }
        float rs = rsqrtf(vv*(1.0f/DD) + EPSV);
        float ov[DD];
#pragma unroll
        for (int o = 0; o < DD; ++o) ov[o] = (f2[o]-mu)*rs*sg2[o] + sb2[o];
        float4* op = (float4*)(out + ((size_t)blockIdx.x*FTOK + tid)*DD);
#pragma unroll
        for (int i = 0; i < DD/4; ++i)
            op[i] = make_float4(ov[4*i+0], ov[4*i+1], ov[4*i+2], ov[4*i+3]);
    }
}

extern "C" void kernel_launch(void* const* d_in, const int* in_sizes, int n_in,
                              void* d_out, int out_size, void* d_ws, size_t ws_size,
                              hipStream_t stream) {
    const float* x  = (const float*)d_in[0];
    const float* Wq = (const float*)d_in[1];
    const float* Wk = (const float*)d_in[2];
    const float* Wv = (const float*)d_in[3];
    const float* Wo = (const float*)d_in[4];
    const float* W1 = (const float*)d_in[5];
    const float* W2 = (const float*)d_in[6];
    const float* g1 = (const float*)d_in[7];
    const float* b1 = (const float*)d_in[8];
    const float* g2 = (const float*)d_in[9];
    const float* b2 = (const float*)d_in[10];
    float* out = (float*)d_out;

    ushort_t* Oa = (ushort_t*)d_ws;   // bf16 Oa scratch

    attn_kernel<<<NBH, 512, 0, stream>>>(x, Wq, Wk, Wv, Oa);
    ffn_kernel<<<NTOK/FTOK, 128, 0, stream>>>(x, Oa, Wo, W1, W2, g1, b1, g2, b2, out);
}